// Round 19
// baseline (577.443 us; speedup 1.0000x reference)
//
#include <hip/hip_runtime.h>
#include <hip/hip_bf16.h>

typedef __bf16 bf16_t;
typedef __attribute__((ext_vector_type(4))) __bf16 bf16x4;
typedef __attribute__((ext_vector_type(8))) __bf16 bf16x8;
typedef __attribute__((ext_vector_type(4))) float f32x4;

#define DIM   4096
#define NQKV  6144
#define S_LEN 2048
#define HD    128

__device__ __forceinline__ void gload_lds16(const void* g, void* l) {
  __builtin_amdgcn_global_load_lds(
      (__attribute__((address_space(1))) void*)(g),
      (__attribute__((address_space(3))) void*)(l), 16, 0, 0);
}

// fp32 -> bf16 elementwise
__global__ __launch_bounds__(256) void convert_bf16(const float* __restrict__ src,
                                                    bf16_t* __restrict__ dst) {
  size_t i = ((size_t)blockIdx.x * 256 + threadIdx.x) * 8;
  f32x4 a = *(const f32x4*)(src + i);
  f32x4 b = *(const f32x4*)(src + i + 4);
  bf16x8 o;
#pragma unroll
  for (int j = 0; j < 4; ++j) { o[j] = (bf16_t)a[j]; o[4 + j] = (bf16_t)b[j]; }
  *(bf16x8*)(dst + i) = o;
}

// all 4 weight transposes in one dispatch: dst[n*4096 + k] = (bf16) src[k*N + n]
__global__ __launch_bounds__(256) void transpose_all(const float* __restrict__ wq,
                                                     const float* __restrict__ wk,
                                                     const float* __restrict__ wv,
                                                     const float* __restrict__ wo,
                                                     bf16_t* __restrict__ wqkvT,
                                                     bf16_t* __restrict__ woT) {
  __shared__ float tile[64][65];
  int blk = blockIdx.x;
  const float* src; bf16_t* dst; int N, by, bx;
  if (blk < 4096)      { src = wq; dst = wqkvT;                        N = 4096; by = blk >> 6; bx = blk & 63; }
  else if (blk < 5120) { blk -= 4096; src = wk; dst = wqkvT + (size_t)4096 * 4096; N = 1024; by = blk >> 4; bx = blk & 15; }
  else if (blk < 6144) { blk -= 5120; src = wv; dst = wqkvT + (size_t)5120 * 4096; N = 1024; by = blk >> 4; bx = blk & 15; }
  else                 { blk -= 6144; src = wo; dst = woT;             N = 4096; by = blk >> 6; bx = blk & 63; }
  const int k0 = by * 64, n0 = bx * 64;
  const int t = threadIdx.x;
#pragma unroll
  for (int p = 0; p < 4; ++p) {
    int idx = p * 256 + t;
    int r = idx >> 4, c4 = (idx & 15) * 4;
    f32x4 v = *(const f32x4*)&src[(size_t)(k0 + r) * N + n0 + c4];
    tile[r][c4] = v[0]; tile[r][c4 + 1] = v[1];
    tile[r][c4 + 2] = v[2]; tile[r][c4 + 3] = v[3];
  }
  __syncthreads();
#pragma unroll
  for (int p = 0; p < 4; ++p) {
    int idx = p * 256 + t;
    int r = idx >> 4, c4 = (idx & 15) * 4;
    bf16x4 o;
    o[0] = (bf16_t)tile[c4][r];     o[1] = (bf16_t)tile[c4 + 1][r];
    o[2] = (bf16_t)tile[c4 + 2][r]; o[3] = (bf16_t)tile[c4 + 3][r];
    *(bf16x4*)&dst[(size_t)(n0 + r) * 4096 + k0 + c4] = o;
  }
}

// ---- 256x256 8-phase GEMM, K=4096 fixed (64 K-tiles of BK=64) ----
template <typename CT, bool ROPE>
__global__ __launch_bounds__(512) void gemm256(const bf16_t* __restrict__ A,
                                               const bf16_t* __restrict__ Bt,
                                               CT* __restrict__ C,
                                               int ldc, int nbx, int col0,
                                               const float* __restrict__ cosT,
                                               const float* __restrict__ sinT) {
  __shared__ __align__(16) bf16_t As[32768];   // 64 KB
  __shared__ __align__(16) bf16_t Bs[32768];   // 64 KB
  const int tid  = threadIdx.x;
  const int lane = tid & 63;
  const int w    = tid >> 6;
  const int wm   = w >> 2, wn = w & 3;
  const int l15 = lane & 15, l4 = lane >> 4, l7 = lane & 7;

  const int cpx = gridDim.x >> 3;
  const int swz = (blockIdx.x & 7) * cpx + (blockIdx.x >> 3);
  const int by = swz / nbx, bx = swz - by * nbx;
  const int bm = by * 256, bn = bx * 256;

  const size_t g_off0 = (size_t)((w * 2 + 0) * 8 + (lane >> 3)) * 4096
                      + (((lane & 7) ^ ((lane >> 3) & 7)) * 8);
  const size_t g_off1 = g_off0 + (size_t)8 * 4096;
  const int l_off0 = (w * 2 + 0) * 512;
  const int l_off1 = (w * 2 + 1) * 512;

#define STAGE(gsrc, ldst) do { \
    gload_lds16((gsrc) + g_off0, (ldst) + l_off0); \
    gload_lds16((gsrc) + g_off1, (ldst) + l_off1); } while (0)

  const bf16_t* Ab = A  + (size_t)bm * 4096;
  const bf16_t* Bb = Bt + (size_t)bn * 4096;
  const size_t HLF = (size_t)128 * 4096;

  f32x4 acc[8][4];
#pragma unroll
  for (int i = 0; i < 8; ++i)
#pragma unroll
    for (int j = 0; j < 4; ++j) { f32x4 z = {0.f, 0.f, 0.f, 0.f}; acc[i][j] = z; }

  STAGE(Bb,             Bs);
  STAGE(Ab,             As);
  STAGE(Bb + HLF,       Bs + 8192);
  STAGE(Ab + HLF,       As + 8192);
  STAGE(Bb + 64,        Bs + 16384);
  STAGE(Ab + 64,        As + 16384);
  STAGE(Bb + HLF + 64,  Bs + 16384 + 8192);
  asm volatile("s_waitcnt vmcnt(6)" ::: "memory");
  __builtin_amdgcn_s_barrier();

  for (int t = 0; t < 64; ++t) {
    const int cu = t & 1;
    bf16_t* Ac = As + cu * 16384;
    bf16_t* Bc = Bs + cu * 16384;
    bf16_t* Axn = As + (cu ^ 1) * 16384;
    const bf16_t* A1g = Ab + (size_t)(t + 1) * 64;
    const bf16_t* A2g = Ab + (size_t)(t + 2) * 64;
    const bf16_t* B2g = Bb + (size_t)(t + 2) * 64;

    bf16x8 af[4][2], b0[2][2], b1[2][2];

    // ===== phase 0 =====
#pragma unroll
    for (int f = 0; f < 4; ++f)
#pragma unroll
      for (int kh = 0; kh < 2; ++kh)
        af[f][kh] = *(const bf16x8*)&Ac[(wm * 64 + f * 16 + l15) * 64 + (((kh * 4 + l4) ^ l7) * 8)];
#pragma unroll
    for (int fb = 0; fb < 2; ++fb)
#pragma unroll
      for (int kh = 0; kh < 2; ++kh)
        b0[fb][kh] = *(const bf16x8*)&Bc[(wn * 32 + fb * 16 + l15) * 64 + (((kh * 4 + l4) ^ l7) * 8)];
    if (t + 1 < 64) STAGE(A1g + HLF, Axn + 8192);
    __builtin_amdgcn_s_barrier();
    __builtin_amdgcn_s_setprio(1);
#pragma unroll
    for (int f = 0; f < 4; ++f)
#pragma unroll
      for (int fb = 0; fb < 2; ++fb)
#pragma unroll
        for (int kh = 0; kh < 2; ++kh)
          acc[f][fb] = __builtin_amdgcn_mfma_f32_16x16x32_bf16(af[f][kh], b0[fb][kh], acc[f][fb], 0, 0, 0);
    __builtin_amdgcn_s_setprio(0);
    __builtin_amdgcn_s_barrier();

    // ===== phase 1 =====
#pragma unroll
    for (int fb = 0; fb < 2; ++fb)
#pragma unroll
      for (int kh = 0; kh < 2; ++kh)
        b1[fb][kh] = *(const bf16x8*)&Bc[8192 + (wn * 32 + fb * 16 + l15) * 64 + (((kh * 4 + l4) ^ l7) * 8)];
    if (t + 2 < 64) STAGE(B2g, Bc);
    __builtin_amdgcn_s_barrier();
    __builtin_amdgcn_s_setprio(1);
#pragma unroll
    for (int f = 0; f < 4; ++f)
#pragma unroll
      for (int fb = 0; fb < 2; ++fb)
#pragma unroll
        for (int kh = 0; kh < 2; ++kh)
          acc[f][2 + fb] = __builtin_amdgcn_mfma_f32_16x16x32_bf16(af[f][kh], b1[fb][kh], acc[f][2 + fb], 0, 0, 0);
    __builtin_amdgcn_s_setprio(0);
    __builtin_amdgcn_s_barrier();

    // ===== phase 2 =====
#pragma unroll
    for (int f = 0; f < 4; ++f)
#pragma unroll
      for (int kh = 0; kh < 2; ++kh)
        af[f][kh] = *(const bf16x8*)&Ac[8192 + (wm * 64 + f * 16 + l15) * 64 + (((kh * 4 + l4) ^ l7) * 8)];
    if (t + 2 < 64) STAGE(A2g, Ac);
    __builtin_amdgcn_s_barrier();
    __builtin_amdgcn_s_setprio(1);
#pragma unroll
    for (int f = 0; f < 4; ++f)
#pragma unroll
      for (int fb = 0; fb < 2; ++fb)
#pragma unroll
        for (int kh = 0; kh < 2; ++kh)
          acc[4 + f][fb] = __builtin_amdgcn_mfma_f32_16x16x32_bf16(af[f][kh], b0[fb][kh], acc[4 + f][fb], 0, 0, 0);
    __builtin_amdgcn_s_setprio(0);
    __builtin_amdgcn_s_barrier();

    // ===== phase 3 =====
    if (t + 2 < 64) STAGE(B2g + HLF, Bc + 8192);
    __builtin_amdgcn_s_barrier();
    __builtin_amdgcn_s_setprio(1);
#pragma unroll
    for (int f = 0; f < 4; ++f)
#pragma unroll
      for (int fb = 0; fb < 2; ++fb)
#pragma unroll
        for (int kh = 0; kh < 2; ++kh)
          acc[4 + f][2 + fb] = __builtin_amdgcn_mfma_f32_16x16x32_bf16(af[f][kh], b1[fb][kh], acc[4 + f][2 + fb], 0, 0, 0);
    __builtin_amdgcn_s_setprio(0);
    if (t < 62)       asm volatile("s_waitcnt vmcnt(6)" ::: "memory");
    else if (t == 62) asm volatile("s_waitcnt vmcnt(0)" ::: "memory");
    __builtin_amdgcn_s_barrier();
  }
#undef STAGE

  // ---- epilogue (optionally rope-fused) ----
#pragma unroll
  for (int mi = 0; mi < 8; ++mi) {
    int row0 = bm + (mi >> 2) * 128 + wm * 64 + (mi & 3) * 16 + l4 * 4;
#pragma unroll
    for (int ni = 0; ni < 4; ++ni) {
      int col = bn + (ni >> 1) * 128 + wn * 32 + (ni & 1) * 16 + l15;
      int gcol = col0 + col;
      if (ROPE && gcol < 5120) {
        const int i = (gcol & 127) >> 1;
        const float scl = (gcol < 4096) ? 0.12751745f : 1.0f;
#pragma unroll
        for (int r = 0; r < 4; ++r) {
          int srow = (row0 + r) & (S_LEN - 1);
          float c = cosT[srow * 64 + i] * scl;
          float s = sinT[srow * 64 + i] * scl;
          float a = acc[mi][ni][r];
          float p = __shfl_xor(a, 1);
          float o = (l15 & 1) ? (p * s + a * c) : (a * c - p * s);
          C[(size_t)(row0 + r) * ldc + gcol] = (CT)o;
        }
      } else {
#pragma unroll
        for (int r = 0; r < 4; ++r)
          C[(size_t)(row0 + r) * ldc + gcol] = (CT)acc[mi][ni][r];
      }
    }
  }
}

// ---- 128x256-tile GEMM (KV projection: M=4096, N=2048, K=4096) ----
template <typename CT, bool ROPE>
__global__ __launch_bounds__(512) void gemm128(const bf16_t* __restrict__ A,
                                               const bf16_t* __restrict__ Bt,
                                               CT* __restrict__ C,
                                               int ldc, int nbx, int col0,
                                               const float* __restrict__ cosT,
                                               const float* __restrict__ sinT) {
  __shared__ __align__(16) bf16_t As[2][8192];    // 32 KB
  __shared__ __align__(16) bf16_t Bs[2][16384];   // 64 KB
  const int tid  = threadIdx.x;
  const int lane = tid & 63;
  const int w    = tid >> 6;
  const int wm   = w >> 2, wn = w & 3;
  const int l15 = lane & 15, l4 = lane >> 4, l7 = lane & 7;

  const int cpx = gridDim.x >> 3;
  const int swz = (blockIdx.x & 7) * cpx + (blockIdx.x >> 3);
  const int by = swz / nbx, bx = swz - by * nbx;
  const int bm = by * 128, bn = bx * 256;

  const size_t g_off0 = (size_t)((w * 2 + 0) * 8 + (lane >> 3)) * 4096
                      + (((lane & 7) ^ ((lane >> 3) & 7)) * 8);
  const size_t g_off1 = g_off0 + (size_t)8 * 4096;
  const int l_off0 = (w * 2 + 0) * 512;
  const int l_off1 = (w * 2 + 1) * 512;

#define STAGE(gsrc, ldst) do { \
    gload_lds16((gsrc) + g_off0, (ldst) + l_off0); \
    gload_lds16((gsrc) + g_off1, (ldst) + l_off1); } while (0)

  const bf16_t* Ab = A  + (size_t)bm * 4096;
  const bf16_t* Bb = Bt + (size_t)bn * 4096;
  const size_t HLF = (size_t)128 * 4096;

  f32x4 acc[4][4];
#pragma unroll
  for (int i = 0; i < 4; ++i)
#pragma unroll
    for (int j = 0; j < 4; ++j) { f32x4 z = {0.f, 0.f, 0.f, 0.f}; acc[i][j] = z; }

  STAGE(Ab,        &As[0][0]);
  STAGE(Bb,        &Bs[0][0]);
  STAGE(Bb + HLF,  &Bs[0][8192]);
  STAGE(Bb + 64,   &Bs[1][0]);
  asm volatile("s_waitcnt vmcnt(2)" ::: "memory");
  __builtin_amdgcn_s_barrier();

  for (int t = 0; t < 64; ++t) {
    const int cu = t & 1;
    const bf16_t* A1g = Ab + (size_t)(t + 1) * 64;
    const bf16_t* B1g = Bb + (size_t)(t + 1) * 64;
    const bf16_t* B2g = Bb + (size_t)(t + 2) * 64;

    bf16x8 af[4][2], bl[2][2], bh[2][2];

    // ===== phase 0 =====
#pragma unroll
    for (int f = 0; f < 4; ++f)
#pragma unroll
      for (int kh = 0; kh < 2; ++kh)
        af[f][kh] = *(const bf16x8*)&As[cu][(wm * 64 + f * 16 + l15) * 64 + (((kh * 4 + l4) ^ l7) * 8)];
#pragma unroll
    for (int fb = 0; fb < 2; ++fb)
#pragma unroll
      for (int kh = 0; kh < 2; ++kh)
        bl[fb][kh] = *(const bf16x8*)&Bs[cu][(wn * 32 + fb * 16 + l15) * 64 + (((kh * 4 + l4) ^ l7) * 8)];
    if (t + 1 < 64) {
      STAGE(A1g,       &As[cu ^ 1][0]);
      STAGE(B1g + HLF, &Bs[cu ^ 1][8192]);
    }
    __builtin_amdgcn_s_barrier();
    __builtin_amdgcn_s_setprio(1);
#pragma unroll
    for (int f = 0; f < 4; ++f)
#pragma unroll
      for (int fb = 0; fb < 2; ++fb)
#pragma unroll
        for (int kh = 0; kh < 2; ++kh)
          acc[f][fb] = __builtin_amdgcn_mfma_f32_16x16x32_bf16(af[f][kh], bl[fb][kh], acc[f][fb], 0, 0, 0);
    __builtin_amdgcn_s_setprio(0);
    __builtin_amdgcn_s_barrier();

    // ===== phase 1 =====
#pragma unroll
    for (int fb = 0; fb < 2; ++fb)
#pragma unroll
      for (int kh = 0; kh < 2; ++kh)
        bh[fb][kh] = *(const bf16x8*)&Bs[cu][8192 + (wn * 32 + fb * 16 + l15) * 64 + (((kh * 4 + l4) ^ l7) * 8)];
    if (t + 2 < 64) STAGE(B2g, &Bs[cu][0]);
    __builtin_amdgcn_s_barrier();
    __builtin_amdgcn_s_setprio(1);
#pragma unroll
    for (int f = 0; f < 4; ++f)
#pragma unroll
      for (int fb = 0; fb < 2; ++fb)
#pragma unroll
        for (int kh = 0; kh < 2; ++kh)
          acc[f][2 + fb] = __builtin_amdgcn_mfma_f32_16x16x32_bf16(af[f][kh], bh[fb][kh], acc[f][2 + fb], 0, 0, 0);
    __builtin_amdgcn_s_setprio(0);
    if (t + 2 < 64) asm volatile("s_waitcnt vmcnt(2)" ::: "memory");
    else            asm volatile("s_waitcnt vmcnt(0)" ::: "memory");
    __builtin_amdgcn_s_barrier();
  }
#undef STAGE

  // ---- epilogue (SPLIT column mapping) ----
#pragma unroll
  for (int f = 0; f < 4; ++f) {
    int row0 = bm + wm * 64 + f * 16 + l4 * 4;
#pragma unroll
    for (int fb = 0; fb < 4; ++fb) {
      int col = bn + (fb >> 1) * 128 + wn * 32 + (fb & 1) * 16 + l15;
      int gcol = col0 + col;
      if (ROPE && gcol < 5120) {
        const int i = (gcol & 127) >> 1;
        const float scl = (gcol < 4096) ? 0.12751745f : 1.0f;
#pragma unroll
        for (int r = 0; r < 4; ++r) {
          int srow = (row0 + r) & (S_LEN - 1);
          float c = cosT[srow * 64 + i] * scl;
          float s = sinT[srow * 64 + i] * scl;
          float a = acc[f][fb][r];
          float p = __shfl_xor(a, 1);
          float o = (l15 & 1) ? (p * s + a * c) : (a * c - p * s);
          C[(size_t)(row0 + r) * ldc + gcol] = (CT)o;
        }
      } else {
#pragma unroll
        for (int r = 0; r < 4; ++r)
          C[(size_t)(row0 + r) * ldc + gcol] = (CT)acc[f][fb][r];
      }
    }
  }
}

// causal GQA flash attention: grid (8, 32, 2) = 512 blocks, 8 waves, QB=256.
// UNPAIRED, weight-interleaved dispatch (qt map {7,0,6,1,5,2,4,3}) so per-CU
// block pairs are balanced; 48KB LDS -> 2 blocks/CU co-resident (one block's
// MFMA/staging hides the other's softmax VALU). Round-15 KVBLK=64 pipeline.
__global__ __launch_bounds__(512) void attn_fwd(const bf16_t* __restrict__ qkv,
                                                bf16_t* __restrict__ out) {
  const int qtmap[8] = {7, 0, 6, 1, 5, 2, 4, 3};
  const int qt = qtmap[blockIdx.x & 7];
  const int h  = blockIdx.y;
  const int b  = blockIdx.z;
  const int kvh = h >> 2;
  const int tid = threadIdx.x;
  const int w    = tid >> 6;                 // 0..7
  const int lane = tid & 63;
  const int qloc = lane & 15;
  const int g    = lane >> 4;

  __shared__ __align__(16) bf16_t Ks[2][64 * 128];   // 32 KB
  __shared__ __align__(16) bf16_t Vt[128 * 64];      // 16 KB

  const bf16_t* kvbase = qkv + (size_t)b * S_LEN * NQKV + DIM + kvh * HD;
  const int vrow_t = tid >> 4;               // 0..31
  const int vcol_t = (tid & 15) * 8;

  const float M2 = 11.5415603f;   // 8 * log2(e)
  const int W = qt * 256 + w * 32;
  const int nt = 4 * qt + 4;

  bf16x8 aq[2][4];
#pragma unroll
  for (int qb = 0; qb < 2; ++qb) {
    const bf16_t* qptr = qkv + (size_t)(b * S_LEN + W + qb * 16 + qloc) * NQKV + h * HD + g * 8;
#pragma unroll
    for (int c = 0; c < 4; ++c) aq[qb][c] = *(const bf16x8*)(qptr + c * 32);
  }

  f32x4 oacc[2][8];
  float lsum[2] = {0.f, 0.f};
#pragma unroll
  for (int qb = 0; qb < 2; ++qb)
#pragma unroll
    for (int d = 0; d < 8; ++d) { f32x4 z = {0.f, 0.f, 0.f, 0.f}; oacc[qb][d] = z; }

  bf16x8 vreg[2];
#pragma unroll
  for (int p = 0; p < 2; ++p) {
    int chunk = p * 8 + w;
    int krow = chunk * 4 + g;
    int key = (krow & 3) | (((krow >> 3) & 1) << 2);
    gload_lds16(kvbase + (size_t)krow * NQKV + ((qloc ^ key) * 8), &Ks[0][chunk * 512]);
  }
#pragma unroll
  for (int p = 0; p < 2; ++p)
    vreg[p] = *(const bf16x8*)(kvbase + 1024 + (size_t)(p * 32 + vrow_t) * NQKV + vcol_t);

#pragma unroll 1
  for (int t = 0; t < nt; ++t) {
    const int kv0 = t * 64;
    const int cur = t & 1;

    if (t + 1 < nt) {
      const int kvn = kv0 + 64;
#pragma unroll
      for (int p = 0; p < 2; ++p) {
        int chunk = p * 8 + w;
        int krow = chunk * 4 + g;
        int key = (krow & 3) | (((krow >> 3) & 1) << 2);
        gload_lds16(kvbase + (size_t)(kvn + krow) * NQKV + ((qloc ^ key) * 8),
                    &Ks[cur ^ 1][chunk * 512]);
      }
      asm volatile("s_waitcnt vmcnt(2)" ::: "memory");   // K(t),V(t) done; K(t+1) in flight
    } else {
      asm volatile("s_waitcnt vmcnt(0)" ::: "memory");
    }

    // scatter V(t) -> swizzled Vt
#pragma unroll
    for (int p = 0; p < 2; ++p) {
      int vrow = p * 32 + vrow_t;
      int rk = (vrow >> 3) ^ (tid & 7);
#pragma unroll
      for (int j = 0; j < 8; ++j)
        Vt[(vcol_t + j) * 64 + ((rk ^ j) * 8) + (vrow & 7)] = vreg[p][j];
    }
    if (t + 1 < nt) {
      const int kvn = kv0 + 64;
#pragma unroll
      for (int p = 0; p < 2; ++p)
        vreg[p] = *(const bf16x8*)(kvbase + 1024 + (size_t)(kvn + p * 32 + vrow_t) * NQKV + vcol_t);
    }
    asm volatile("s_waitcnt lgkmcnt(0)" ::: "memory");
    __builtin_amdgcn_s_barrier();

    if (kv0 <= W + 31) {
      f32x4 sacc[2][2][2];
#pragma unroll
      for (int qb = 0; qb < 2; ++qb)
#pragma unroll
        for (int w2 = 0; w2 < 2; ++w2)
#pragma unroll
          for (int hf = 0; hf < 2; ++hf) { f32x4 z = {0.f, 0.f, 0.f, 0.f}; sacc[qb][w2][hf] = z; }
#pragma unroll
      for (int w2 = 0; w2 < 2; ++w2)
#pragma unroll
        for (int hf = 0; hf < 2; ++hf) {
          int r = 32 * w2 + 8 * (qloc >> 2) + 4 * hf + (qloc & 3);
          int key = (r & 3) | (((r >> 3) & 1) << 2);
          bf16x8 bk[4];
#pragma unroll
          for (int c = 0; c < 4; ++c)
            bk[c] = *(const bf16x8*)&Ks[cur][r * 128 + (((c * 4 + g) ^ key) * 8)];
          __builtin_amdgcn_s_setprio(1);
#pragma unroll
          for (int qb = 0; qb < 2; ++qb)
#pragma unroll
            for (int c = 0; c < 4; ++c)
              sacc[qb][w2][hf] = __builtin_amdgcn_mfma_f32_16x16x32_bf16(bk[c], aq[qb][c], sacc[qb][w2][hf], 0, 0, 0);
          __builtin_amdgcn_s_setprio(0);
        }

      const bool diag = (kv0 + 63 > W);
      bf16x8 pa[2][2];
#pragma unroll
      for (int qb = 0; qb < 2; ++qb) {
        const int qg = W + qb * 16 + qloc;
#pragma unroll
        for (int w2 = 0; w2 < 2; ++w2)
#pragma unroll
          for (int hf = 0; hf < 2; ++hf)
#pragma unroll
            for (int r = 0; r < 4; ++r) {
              float e = exp2f(sacc[qb][w2][hf][r] - M2);
              if (diag) {
                int kg = kv0 + 32 * w2 + 8 * g + 4 * hf + r;
                e = (kg <= qg) ? e : 0.f;
              }
              lsum[qb] += e;
              pa[qb][w2][hf * 4 + r] = (bf16_t)e;
            }
      }

#pragma unroll
      for (int w2 = 0; w2 < 2; ++w2)
#pragma unroll
        for (int dt = 0; dt < 8; ++dt) {
          int d = dt * 16 + qloc;
          int key2 = (4 * w2 + g) ^ (d & 7) ^ ((d >> 3) & 7);
          bf16x8 bv = *(const bf16x8*)&Vt[d * 64 + key2 * 8];
          __builtin_amdgcn_s_setprio(1);
#pragma unroll
          for (int qb = 0; qb < 2; ++qb)
            oacc[qb][dt] = __builtin_amdgcn_mfma_f32_16x16x32_bf16(bv, pa[qb][w2], oacc[qb][dt], 0, 0, 0);
          __builtin_amdgcn_s_setprio(0);
        }
    }
    __builtin_amdgcn_s_barrier();
  }

#pragma unroll
  for (int qb = 0; qb < 2; ++qb) {
    float ls = lsum[qb];
    ls += __shfl_xor(ls, 16);
    ls += __shfl_xor(ls, 32);
    float inv = 1.f / ls;
    bf16_t* op = out + (size_t)(b * S_LEN + W + qb * 16 + qloc) * DIM + h * HD;
#pragma unroll
    for (int dt = 0; dt < 8; ++dt) {
      bf16x4 o4;
#pragma unroll
      for (int r = 0; r < 4; ++r) o4[r] = (bf16_t)(oacc[qb][dt][r] * inv);
      *(bf16x4*)(op + dt * 16 + 4 * g) = o4;
    }
  }
}

extern "C" void kernel_launch(void* const* d_in, const int* in_sizes, int n_in,
                              void* d_out, int out_size, void* d_ws, size_t ws_size,
                              hipStream_t stream) {
  const float* x  = (const float*)d_in[0];
  const float* wq = (const float*)d_in[1];
  const float* wk = (const float*)d_in[2];
  const float* wv = (const float*)d_in[3];
  const float* wo = (const float*)d_in[4];
  const float* fc = (const float*)d_in[5];
  const float* fs = (const float*)d_in[6];

  bf16_t* ws    = (bf16_t*)d_ws;
  bf16_t* wqkvT = ws;                                  // 6144*4096 bf16
  bf16_t* woT   = wqkvT + (size_t)6144 * 4096;         // 4096*4096
  bf16_t* qkv   = woT   + (size_t)4096 * 4096;         // 4096*6144
  bf16_t* xb    = qkv   + (size_t)4096 * 6144;         // 4096*4096 (reused as ao)
  bf16_t* ao    = xb;

  convert_bf16<<<8192, 256, 0, stream>>>(x, xb);
  transpose_all<<<10240, 256, 0, stream>>>(wq, wk, wv, wo, wqkvT, woT);

  gemm256<bf16_t, true><<<256, 512, 0, stream>>>(xb, wqkvT, qkv, 6144, 16, 0, fc, fs);
  gemm128<bf16_t, true><<<256, 512, 0, stream>>>(xb, wqkvT + (size_t)4096 * 4096, qkv,
                                                 6144, 8, 4096, fc, fs);
  attn_fwd<<<dim3(8, 32, 2), 512, 0, stream>>>(qkv, ao);
  gemm256<float, false><<<256, 512, 0, stream>>>(ao, woT, (float*)d_out, 4096, 16, 0, nullptr, nullptr);
}

// Round 20
// 490.929 us; speedup vs baseline: 1.1762x; 1.1762x over previous
//
#include <hip/hip_runtime.h>
#include <hip/hip_bf16.h>

typedef __bf16 bf16_t;
typedef __attribute__((ext_vector_type(4))) __bf16 bf16x4;
typedef __attribute__((ext_vector_type(8))) __bf16 bf16x8;
typedef __attribute__((ext_vector_type(4))) float f32x4;

#define DIM   4096
#define NQKV  6144
#define S_LEN 2048
#define HD    128

__device__ __forceinline__ void gload_lds16(const void* g, void* l) {
  __builtin_amdgcn_global_load_lds(
      (__attribute__((address_space(1))) void*)(g),
      (__attribute__((address_space(3))) void*)(l), 16, 0, 0);
}

// fp32 -> bf16 elementwise
__global__ __launch_bounds__(256) void convert_bf16(const float* __restrict__ src,
                                                    bf16_t* __restrict__ dst) {
  size_t i = ((size_t)blockIdx.x * 256 + threadIdx.x) * 8;
  f32x4 a = *(const f32x4*)(src + i);
  f32x4 b = *(const f32x4*)(src + i + 4);
  bf16x8 o;
#pragma unroll
  for (int j = 0; j < 4; ++j) { o[j] = (bf16_t)a[j]; o[4 + j] = (bf16_t)b[j]; }
  *(bf16x8*)(dst + i) = o;
}

// all 4 weight transposes in one dispatch: dst[n*4096 + k] = (bf16) src[k*N + n]
__global__ __launch_bounds__(256) void transpose_all(const float* __restrict__ wq,
                                                     const float* __restrict__ wk,
                                                     const float* __restrict__ wv,
                                                     const float* __restrict__ wo,
                                                     bf16_t* __restrict__ wqkvT,
                                                     bf16_t* __restrict__ woT) {
  __shared__ float tile[64][65];
  int blk = blockIdx.x;
  const float* src; bf16_t* dst; int N, by, bx;
  if (blk < 4096)      { src = wq; dst = wqkvT;                        N = 4096; by = blk >> 6; bx = blk & 63; }
  else if (blk < 5120) { blk -= 4096; src = wk; dst = wqkvT + (size_t)4096 * 4096; N = 1024; by = blk >> 4; bx = blk & 15; }
  else if (blk < 6144) { blk -= 5120; src = wv; dst = wqkvT + (size_t)5120 * 4096; N = 1024; by = blk >> 4; bx = blk & 15; }
  else                 { blk -= 6144; src = wo; dst = woT;             N = 4096; by = blk >> 6; bx = blk & 63; }
  const int k0 = by * 64, n0 = bx * 64;
  const int t = threadIdx.x;
#pragma unroll
  for (int p = 0; p < 4; ++p) {
    int idx = p * 256 + t;
    int r = idx >> 4, c4 = (idx & 15) * 4;
    f32x4 v = *(const f32x4*)&src[(size_t)(k0 + r) * N + n0 + c4];
    tile[r][c4] = v[0]; tile[r][c4 + 1] = v[1];
    tile[r][c4 + 2] = v[2]; tile[r][c4 + 3] = v[3];
  }
  __syncthreads();
#pragma unroll
  for (int p = 0; p < 4; ++p) {
    int idx = p * 256 + t;
    int r = idx >> 4, c4 = (idx & 15) * 4;
    bf16x4 o;
    o[0] = (bf16_t)tile[c4][r];     o[1] = (bf16_t)tile[c4 + 1][r];
    o[2] = (bf16_t)tile[c4 + 2][r]; o[3] = (bf16_t)tile[c4 + 3][r];
    *(bf16x4*)&dst[(size_t)(n0 + r) * 4096 + k0 + c4] = o;
  }
}

// ---- 256x256 8-phase GEMM, K=4096 fixed (64 K-tiles of BK=64) ----
// NOTE: no explicit lgkmcnt/sched_barrier in phases — IR ds_reads let the
// compiler emit fine-grained lgkm waits (m97); hard fences only pin (m141).
template <typename CT, bool ROPE>
__global__ __launch_bounds__(512) void gemm256(const bf16_t* __restrict__ A,
                                               const bf16_t* __restrict__ Bt,
                                               CT* __restrict__ C,
                                               int ldc, int nbx, int col0,
                                               const float* __restrict__ cosT,
                                               const float* __restrict__ sinT) {
  __shared__ __align__(16) bf16_t As[32768];   // 64 KB
  __shared__ __align__(16) bf16_t Bs[32768];   // 64 KB
  const int tid  = threadIdx.x;
  const int lane = tid & 63;
  const int w    = tid >> 6;
  const int wm   = w >> 2, wn = w & 3;
  const int l15 = lane & 15, l4 = lane >> 4, l7 = lane & 7;

  const int cpx = gridDim.x >> 3;
  const int swz = (blockIdx.x & 7) * cpx + (blockIdx.x >> 3);
  const int by = swz / nbx, bx = swz - by * nbx;
  const int bm = by * 256, bn = bx * 256;

  const size_t g_off0 = (size_t)((w * 2 + 0) * 8 + (lane >> 3)) * 4096
                      + (((lane & 7) ^ ((lane >> 3) & 7)) * 8);
  const size_t g_off1 = g_off0 + (size_t)8 * 4096;
  const int l_off0 = (w * 2 + 0) * 512;
  const int l_off1 = (w * 2 + 1) * 512;

#define STAGE(gsrc, ldst) do { \
    gload_lds16((gsrc) + g_off0, (ldst) + l_off0); \
    gload_lds16((gsrc) + g_off1, (ldst) + l_off1); } while (0)

  const bf16_t* Ab = A  + (size_t)bm * 4096;
  const bf16_t* Bb = Bt + (size_t)bn * 4096;
  const size_t HLF = (size_t)128 * 4096;

  f32x4 acc[8][4];
#pragma unroll
  for (int i = 0; i < 8; ++i)
#pragma unroll
    for (int j = 0; j < 4; ++j) { f32x4 z = {0.f, 0.f, 0.f, 0.f}; acc[i][j] = z; }

  STAGE(Bb,             Bs);
  STAGE(Ab,             As);
  STAGE(Bb + HLF,       Bs + 8192);
  STAGE(Ab + HLF,       As + 8192);
  STAGE(Bb + 64,        Bs + 16384);
  STAGE(Ab + 64,        As + 16384);
  STAGE(Bb + HLF + 64,  Bs + 16384 + 8192);
  asm volatile("s_waitcnt vmcnt(6)" ::: "memory");
  __builtin_amdgcn_s_barrier();

  for (int t = 0; t < 64; ++t) {
    const int cu = t & 1;
    bf16_t* Ac = As + cu * 16384;
    bf16_t* Bc = Bs + cu * 16384;
    bf16_t* Axn = As + (cu ^ 1) * 16384;
    const bf16_t* A1g = Ab + (size_t)(t + 1) * 64;
    const bf16_t* A2g = Ab + (size_t)(t + 2) * 64;
    const bf16_t* B2g = Bb + (size_t)(t + 2) * 64;

    bf16x8 af[4][2], b0[2][2], b1[2][2];

    // ===== phase 0 =====
#pragma unroll
    for (int f = 0; f < 4; ++f)
#pragma unroll
      for (int kh = 0; kh < 2; ++kh)
        af[f][kh] = *(const bf16x8*)&Ac[(wm * 64 + f * 16 + l15) * 64 + (((kh * 4 + l4) ^ l7) * 8)];
#pragma unroll
    for (int fb = 0; fb < 2; ++fb)
#pragma unroll
      for (int kh = 0; kh < 2; ++kh)
        b0[fb][kh] = *(const bf16x8*)&Bc[(wn * 32 + fb * 16 + l15) * 64 + (((kh * 4 + l4) ^ l7) * 8)];
    if (t + 1 < 64) STAGE(A1g + HLF, Axn + 8192);
    __builtin_amdgcn_s_barrier();
    __builtin_amdgcn_s_setprio(1);
#pragma unroll
    for (int f = 0; f < 4; ++f)
#pragma unroll
      for (int fb = 0; fb < 2; ++fb)
#pragma unroll
        for (int kh = 0; kh < 2; ++kh)
          acc[f][fb] = __builtin_amdgcn_mfma_f32_16x16x32_bf16(af[f][kh], b0[fb][kh], acc[f][fb], 0, 0, 0);
    __builtin_amdgcn_s_setprio(0);
    __builtin_amdgcn_s_barrier();

    // ===== phase 1 =====
#pragma unroll
    for (int fb = 0; fb < 2; ++fb)
#pragma unroll
      for (int kh = 0; kh < 2; ++kh)
        b1[fb][kh] = *(const bf16x8*)&Bc[8192 + (wn * 32 + fb * 16 + l15) * 64 + (((kh * 4 + l4) ^ l7) * 8)];
    if (t + 2 < 64) STAGE(B2g, Bc);
    __builtin_amdgcn_s_barrier();
    __builtin_amdgcn_s_setprio(1);
#pragma unroll
    for (int f = 0; f < 4; ++f)
#pragma unroll
      for (int fb = 0; fb < 2; ++fb)
#pragma unroll
        for (int kh = 0; kh < 2; ++kh)
          acc[f][2 + fb] = __builtin_amdgcn_mfma_f32_16x16x32_bf16(af[f][kh], b1[fb][kh], acc[f][2 + fb], 0, 0, 0);
    __builtin_amdgcn_s_setprio(0);
    __builtin_amdgcn_s_barrier();

    // ===== phase 2 =====
#pragma unroll
    for (int f = 0; f < 4; ++f)
#pragma unroll
      for (int kh = 0; kh < 2; ++kh)
        af[f][kh] = *(const bf16x8*)&Ac[8192 + (wm * 64 + f * 16 + l15) * 64 + (((kh * 4 + l4) ^ l7) * 8)];
    if (t + 2 < 64) STAGE(A2g, Ac);
    __builtin_amdgcn_s_barrier();
    __builtin_amdgcn_s_setprio(1);
#pragma unroll
    for (int f = 0; f < 4; ++f)
#pragma unroll
      for (int fb = 0; fb < 2; ++fb)
#pragma unroll
        for (int kh = 0; kh < 2; ++kh)
          acc[4 + f][fb] = __builtin_amdgcn_mfma_f32_16x16x32_bf16(af[f][kh], b0[fb][kh], acc[4 + f][fb], 0, 0, 0);
    __builtin_amdgcn_s_setprio(0);
    __builtin_amdgcn_s_barrier();

    // ===== phase 3 =====
    if (t + 2 < 64) STAGE(B2g + HLF, Bc + 8192);
    __builtin_amdgcn_s_barrier();
    __builtin_amdgcn_s_setprio(1);
#pragma unroll
    for (int f = 0; f < 4; ++f)
#pragma unroll
      for (int fb = 0; fb < 2; ++fb)
#pragma unroll
        for (int kh = 0; kh < 2; ++kh)
          acc[4 + f][2 + fb] = __builtin_amdgcn_mfma_f32_16x16x32_bf16(af[f][kh], b1[fb][kh], acc[4 + f][2 + fb], 0, 0, 0);
    __builtin_amdgcn_s_setprio(0);
    if (t < 62)       asm volatile("s_waitcnt vmcnt(6)" ::: "memory");
    else if (t == 62) asm volatile("s_waitcnt vmcnt(0)" ::: "memory");
    __builtin_amdgcn_s_barrier();
  }
#undef STAGE

  // ---- epilogue (optionally rope-fused) ----
#pragma unroll
  for (int mi = 0; mi < 8; ++mi) {
    int row0 = bm + (mi >> 2) * 128 + wm * 64 + (mi & 3) * 16 + l4 * 4;
#pragma unroll
    for (int ni = 0; ni < 4; ++ni) {
      int col = bn + (ni >> 1) * 128 + wn * 32 + (ni & 1) * 16 + l15;
      int gcol = col0 + col;
      if (ROPE && gcol < 5120) {
        const int i = (gcol & 127) >> 1;
        const float scl = (gcol < 4096) ? 0.12751745f : 1.0f;
#pragma unroll
        for (int r = 0; r < 4; ++r) {
          int srow = (row0 + r) & (S_LEN - 1);
          float c = cosT[srow * 64 + i] * scl;
          float s = sinT[srow * 64 + i] * scl;
          float a = acc[mi][ni][r];
          float p = __shfl_xor(a, 1);
          float o = (l15 & 1) ? (p * s + a * c) : (a * c - p * s);
          C[(size_t)(row0 + r) * ldc + gcol] = (CT)o;
        }
      } else {
#pragma unroll
        for (int r = 0; r < 4; ++r)
          C[(size_t)(row0 + r) * ldc + gcol] = (CT)acc[mi][ni][r];
      }
    }
  }
}

// ---- 128x256-tile GEMM (KV projection: M=4096, N=2048, K=4096) ----
template <typename CT, bool ROPE>
__global__ __launch_bounds__(512) void gemm128(const bf16_t* __restrict__ A,
                                               const bf16_t* __restrict__ Bt,
                                               CT* __restrict__ C,
                                               int ldc, int nbx, int col0,
                                               const float* __restrict__ cosT,
                                               const float* __restrict__ sinT) {
  __shared__ __align__(16) bf16_t As[2][8192];    // 32 KB
  __shared__ __align__(16) bf16_t Bs[2][16384];   // 64 KB
  const int tid  = threadIdx.x;
  const int lane = tid & 63;
  const int w    = tid >> 6;
  const int wm   = w >> 2, wn = w & 3;
  const int l15 = lane & 15, l4 = lane >> 4, l7 = lane & 7;

  const int cpx = gridDim.x >> 3;
  const int swz = (blockIdx.x & 7) * cpx + (blockIdx.x >> 3);
  const int by = swz / nbx, bx = swz - by * nbx;
  const int bm = by * 128, bn = bx * 256;

  const size_t g_off0 = (size_t)((w * 2 + 0) * 8 + (lane >> 3)) * 4096
                      + (((lane & 7) ^ ((lane >> 3) & 7)) * 8);
  const size_t g_off1 = g_off0 + (size_t)8 * 4096;
  const int l_off0 = (w * 2 + 0) * 512;
  const int l_off1 = (w * 2 + 1) * 512;

#define STAGE(gsrc, ldst) do { \
    gload_lds16((gsrc) + g_off0, (ldst) + l_off0); \
    gload_lds16((gsrc) + g_off1, (ldst) + l_off1); } while (0)

  const bf16_t* Ab = A  + (size_t)bm * 4096;
  const bf16_t* Bb = Bt + (size_t)bn * 4096;
  const size_t HLF = (size_t)128 * 4096;

  f32x4 acc[4][4];
#pragma unroll
  for (int i = 0; i < 4; ++i)
#pragma unroll
    for (int j = 0; j < 4; ++j) { f32x4 z = {0.f, 0.f, 0.f, 0.f}; acc[i][j] = z; }

  STAGE(Ab,        &As[0][0]);
  STAGE(Bb,        &Bs[0][0]);
  STAGE(Bb + HLF,  &Bs[0][8192]);
  STAGE(Bb + 64,   &Bs[1][0]);
  asm volatile("s_waitcnt vmcnt(2)" ::: "memory");
  __builtin_amdgcn_s_barrier();

  for (int t = 0; t < 64; ++t) {
    const int cu = t & 1;
    const bf16_t* A1g = Ab + (size_t)(t + 1) * 64;
    const bf16_t* B1g = Bb + (size_t)(t + 1) * 64;
    const bf16_t* B2g = Bb + (size_t)(t + 2) * 64;

    bf16x8 af[4][2], bl[2][2], bh[2][2];

    // ===== phase 0 =====
#pragma unroll
    for (int f = 0; f < 4; ++f)
#pragma unroll
      for (int kh = 0; kh < 2; ++kh)
        af[f][kh] = *(const bf16x8*)&As[cu][(wm * 64 + f * 16 + l15) * 64 + (((kh * 4 + l4) ^ l7) * 8)];
#pragma unroll
    for (int fb = 0; fb < 2; ++fb)
#pragma unroll
      for (int kh = 0; kh < 2; ++kh)
        bl[fb][kh] = *(const bf16x8*)&Bs[cu][(wn * 32 + fb * 16 + l15) * 64 + (((kh * 4 + l4) ^ l7) * 8)];
    if (t + 1 < 64) {
      STAGE(A1g,       &As[cu ^ 1][0]);
      STAGE(B1g + HLF, &Bs[cu ^ 1][8192]);
    }
    __builtin_amdgcn_s_barrier();
    __builtin_amdgcn_s_setprio(1);
#pragma unroll
    for (int f = 0; f < 4; ++f)
#pragma unroll
      for (int fb = 0; fb < 2; ++fb)
#pragma unroll
        for (int kh = 0; kh < 2; ++kh)
          acc[f][fb] = __builtin_amdgcn_mfma_f32_16x16x32_bf16(af[f][kh], bl[fb][kh], acc[f][fb], 0, 0, 0);
    __builtin_amdgcn_s_setprio(0);
    __builtin_amdgcn_s_barrier();

    // ===== phase 1 =====
#pragma unroll
    for (int fb = 0; fb < 2; ++fb)
#pragma unroll
      for (int kh = 0; kh < 2; ++kh)
        bh[fb][kh] = *(const bf16x8*)&Bs[cu][8192 + (wn * 32 + fb * 16 + l15) * 64 + (((kh * 4 + l4) ^ l7) * 8)];
    if (t + 2 < 64) STAGE(B2g, &Bs[cu][0]);
    __builtin_amdgcn_s_barrier();
    __builtin_amdgcn_s_setprio(1);
#pragma unroll
    for (int f = 0; f < 4; ++f)
#pragma unroll
      for (int fb = 0; fb < 2; ++fb)
#pragma unroll
        for (int kh = 0; kh < 2; ++kh)
          acc[f][2 + fb] = __builtin_amdgcn_mfma_f32_16x16x32_bf16(af[f][kh], bh[fb][kh], acc[f][2 + fb], 0, 0, 0);
    __builtin_amdgcn_s_setprio(0);
    if (t + 2 < 64) asm volatile("s_waitcnt vmcnt(2)" ::: "memory");
    else            asm volatile("s_waitcnt vmcnt(0)" ::: "memory");
    __builtin_amdgcn_s_barrier();
  }
#undef STAGE

  // ---- epilogue (SPLIT column mapping) ----
#pragma unroll
  for (int f = 0; f < 4; ++f) {
    int row0 = bm + wm * 64 + f * 16 + l4 * 4;
#pragma unroll
    for (int fb = 0; fb < 4; ++fb) {
      int col = bn + (fb >> 1) * 128 + wn * 32 + (fb & 1) * 16 + l15;
      int gcol = col0 + col;
      if (ROPE && gcol < 5120) {
        const int i = (gcol & 127) >> 1;
        const float scl = (gcol < 4096) ? 0.12751745f : 1.0f;
#pragma unroll
        for (int r = 0; r < 4; ++r) {
          int srow = (row0 + r) & (S_LEN - 1);
          float c = cosT[srow * 64 + i] * scl;
          float s = sinT[srow * 64 + i] * scl;
          float a = acc[f][fb][r];
          float p = __shfl_xor(a, 1);
          float o = (l15 & 1) ? (p * s + a * c) : (a * c - p * s);
          C[(size_t)(row0 + r) * ldc + gcol] = (CT)o;
        }
      } else {
#pragma unroll
        for (int r = 0; r < 4; ++r)
          C[(size_t)(row0 + r) * ldc + gcol] = (CT)acc[f][fb][r];
      }
    }
  }
}

// causal GQA flash attention: grid (4, 32, 2), 8 waves x 32 q-rows (QB=256).
// WORK-PAIRED (uniform 18 kv-tiles of 128/block). KVBLK=128.
__global__ __launch_bounds__(512) void attn_fwd(const bf16_t* __restrict__ qkv,
                                                bf16_t* __restrict__ out) {
  const int pr = blockIdx.x;                 // 0..3
  const int h  = blockIdx.y;
  const int b  = blockIdx.z;
  const int kvh = h >> 2;
  const int tid = threadIdx.x;
  const int w    = tid >> 6;                 // 0..7
  const int lane = tid & 63;
  const int qloc = lane & 15;
  const int g    = lane >> 4;

  __shared__ __align__(16) bf16_t Ks[2][128 * 128];  // 64 KB
  __shared__ __align__(16) bf16_t Vt[128 * 128];     // 32 KB

  const bf16_t* kvbase = qkv + (size_t)b * S_LEN * NQKV + DIM + kvh * HD;
  const int vrow_t = tid >> 4;               // 0..31
  const int vcol_t = (tid & 15) * 8;

  const float M2 = 11.5415603f;   // 8 * log2(e)

#pragma unroll 1
  for (int half = 0; half < 2; ++half) {
    const int qt = half ? pr : 7 - pr;
    const int W = qt * 256 + w * 32;
    const int nt = 2 * qt + 2;               // kv-tiles of 128

    bf16x8 aq[2][4];
#pragma unroll
    for (int qb = 0; qb < 2; ++qb) {
      const bf16_t* qptr = qkv + (size_t)(b * S_LEN + W + qb * 16 + qloc) * NQKV + h * HD + g * 8;
#pragma unroll
      for (int c = 0; c < 4; ++c) aq[qb][c] = *(const bf16x8*)(qptr + c * 32);
    }

    f32x4 oacc[2][8];
    float lsum[2] = {0.f, 0.f};
#pragma unroll
    for (int qb = 0; qb < 2; ++qb)
#pragma unroll
      for (int d = 0; d < 8; ++d) { f32x4 z = {0.f, 0.f, 0.f, 0.f}; oacc[qb][d] = z; }

    // ---- prologue: K(0) DMA (4), V(0) loads (4) ----
    bf16x8 vreg[4];
#pragma unroll
    for (int p = 0; p < 4; ++p) {
      int chunk = p * 8 + w;                 // 0..31
      int krow = chunk * 4 + g;              // 0..127
      int key = (krow & 3) | (((krow >> 3) & 1) << 2);
      gload_lds16(kvbase + (size_t)krow * NQKV + ((qloc ^ key) * 8), &Ks[0][chunk * 512]);
    }
#pragma unroll
    for (int p = 0; p < 4; ++p)
      vreg[p] = *(const bf16x8*)(kvbase + 1024 + (size_t)(p * 32 + vrow_t) * NQKV + vcol_t);

#pragma unroll 1
    for (int t = 0; t < nt; ++t) {
      const int kv0 = t * 128;
      const int cur = t & 1;

      if (t + 1 < nt) {
        const int kvn = kv0 + 128;
#pragma unroll
        for (int p = 0; p < 4; ++p) {
          int chunk = p * 8 + w;
          int krow = chunk * 4 + g;
          int key = (krow & 3) | (((krow >> 3) & 1) << 2);
          gload_lds16(kvbase + (size_t)(kvn + krow) * NQKV + ((qloc ^ key) * 8),
                      &Ks[cur ^ 1][chunk * 512]);
        }
        asm volatile("s_waitcnt vmcnt(4)" ::: "memory");   // K(t),V(t) done; K(t+1) in flight
      } else {
        asm volatile("s_waitcnt vmcnt(0)" ::: "memory");
      }

      // scatter V(t) -> swizzled Vt[kv stride 128]
#pragma unroll
      for (int p = 0; p < 4; ++p) {
        int vrow = p * 32 + vrow_t;
        int rk = (vrow >> 3) ^ (tid & 7);
#pragma unroll
        for (int j = 0; j < 8; ++j)
          Vt[(vcol_t + j) * 128 + ((rk ^ j) * 8) + (vrow & 7)] = vreg[p][j];
      }
      if (t + 1 < nt) {
        const int kvn = kv0 + 128;
#pragma unroll
        for (int p = 0; p < 4; ++p)
          vreg[p] = *(const bf16x8*)(kvbase + 1024 + (size_t)(kvn + p * 32 + vrow_t) * NQKV + vcol_t);
      }
      asm volatile("s_waitcnt lgkmcnt(0)" ::: "memory");
      __builtin_amdgcn_s_barrier();

      if (kv0 <= W + 31) {
        const bool diag = (kv0 + 127 > W);
#pragma unroll
        for (int w2g = 0; w2g < 2; ++w2g) {
          if (kv0 + 64 * w2g <= W + 31) {    // wave-uniform gate
            f32x4 sacc[2][2][2];             // [qb][w2l][hf]
#pragma unroll
            for (int qb = 0; qb < 2; ++qb)
#pragma unroll
              for (int w2l = 0; w2l < 2; ++w2l)
#pragma unroll
                for (int hf = 0; hf < 2; ++hf) { f32x4 z = {0.f, 0.f, 0.f, 0.f}; sacc[qb][w2l][hf] = z; }
#pragma unroll
            for (int w2l = 0; w2l < 2; ++w2l)
#pragma unroll
              for (int hf = 0; hf < 2; ++hf) {
                int w2 = 2 * w2g + w2l;
                int rr = 32 * w2 + 8 * (qloc >> 2) + 4 * hf + (qloc & 3);
                int key = (rr & 3) | (((rr >> 3) & 1) << 2);
                bf16x8 bk[4];
#pragma unroll
                for (int c = 0; c < 4; ++c)
                  bk[c] = *(const bf16x8*)&Ks[cur][rr * 128 + (((c * 4 + g) ^ key) * 8)];
                __builtin_amdgcn_s_setprio(1);
#pragma unroll
                for (int qb = 0; qb < 2; ++qb)
#pragma unroll
                  for (int c = 0; c < 4; ++c)
                    sacc[qb][w2l][hf] = __builtin_amdgcn_mfma_f32_16x16x32_bf16(bk[c], aq[qb][c], sacc[qb][w2l][hf], 0, 0, 0);
                __builtin_amdgcn_s_setprio(0);
              }

            bf16x8 pa[2][2];
#pragma unroll
            for (int qb = 0; qb < 2; ++qb) {
              const int qg = W + qb * 16 + qloc;
#pragma unroll
              for (int w2l = 0; w2l < 2; ++w2l)
#pragma unroll
                for (int hf = 0; hf < 2; ++hf)
#pragma unroll
                  for (int r = 0; r < 4; ++r) {
                    float e = exp2f(sacc[qb][w2l][hf][r] - M2);
                    if (diag) {
                      int kg = kv0 + 32 * (2 * w2g + w2l) + 8 * g + 4 * hf + r;
                      e = (kg <= qg) ? e : 0.f;
                    }
                    lsum[qb] += e;
                    pa[qb][w2l][hf * 4 + r] = (bf16_t)e;
                  }
            }

#pragma unroll
            for (int w2l = 0; w2l < 2; ++w2l)
#pragma unroll
              for (int dt = 0; dt < 8; ++dt) {
                int w2 = 2 * w2g + w2l;
                int d = dt * 16 + qloc;
                int key2 = (4 * w2 + g) ^ (d & 7) ^ ((d >> 3) & 7);
                bf16x8 bv = *(const bf16x8*)&Vt[d * 128 + key2 * 8];
                __builtin_amdgcn_s_setprio(1);
#pragma unroll
                for (int qb = 0; qb < 2; ++qb)
                  oacc[qb][dt] = __builtin_amdgcn_mfma_f32_16x16x32_bf16(bv, pa[qb][w2l], oacc[qb][dt], 0, 0, 0);
                __builtin_amdgcn_s_setprio(0);
              }
          }
        }
      }
      __builtin_amdgcn_s_barrier();
    }

    // --- epilogue: reduce l over g groups, normalize, store b64 ---
#pragma unroll
    for (int qb = 0; qb < 2; ++qb) {
      float ls = lsum[qb];
      ls += __shfl_xor(ls, 16);
      ls += __shfl_xor(ls, 32);
      float inv = 1.f / ls;
      bf16_t* op = out + (size_t)(b * S_LEN + W + qb * 16 + qloc) * DIM + h * HD;
#pragma unroll
      for (int dt = 0; dt < 8; ++dt) {
        bf16x4 o4;
#pragma unroll
        for (int r = 0; r < 4; ++r) o4[r] = (bf16_t)(oacc[qb][dt][r] * inv);
        *(bf16x4*)(op + dt * 16 + 4 * g) = o4;
      }
    }
  }
}

extern "C" void kernel_launch(void* const* d_in, const int* in_sizes, int n_in,
                              void* d_out, int out_size, void* d_ws, size_t ws_size,
                              hipStream_t stream) {
  const float* x  = (const float*)d_in[0];
  const float* wq = (const float*)d_in[1];
  const float* wk = (const float*)d_in[2];
  const float* wv = (const float*)d_in[3];
  const float* wo = (const float*)d_in[4];
  const float* fc = (const float*)d_in[5];
  const float* fs = (const float*)d_in[6];

  bf16_t* ws    = (bf16_t*)d_ws;
  bf16_t* wqkvT = ws;                                  // 6144*4096 bf16
  bf16_t* woT   = wqkvT + (size_t)6144 * 4096;         // 4096*4096
  bf16_t* qkv   = woT   + (size_t)4096 * 4096;         // 4096*6144
  bf16_t* xb    = qkv   + (size_t)4096 * 6144;         // 4096*4096 (reused as ao)
  bf16_t* ao    = xb;

  convert_bf16<<<8192, 256, 0, stream>>>(x, xb);
  transpose_all<<<10240, 256, 0, stream>>>(wq, wk, wv, wo, wqkvT, woT);

  gemm256<bf16_t, true><<<256, 512, 0, stream>>>(xb, wqkvT, qkv, 6144, 16, 0, fc, fs);
  gemm128<bf16_t, true><<<256, 512, 0, stream>>>(xb, wqkvT + (size_t)4096 * 4096, qkv,
                                                 6144, 8, 4096, fc, fs);
  attn_fwd<<<dim3(4, 32, 2), 512, 0, stream>>>(qkv, ao);
  gemm256<float, false><<<256, 512, 0, stream>>>(ao, woT, (float*)d_out, 4096, 16, 0, nullptr, nullptr);
}